// Round 2
// baseline (1066.416 us; speedup 1.0000x reference)
//
#include <hip/hip_runtime.h>
#include <math.h>

// ---------------------------------------------------------------------------
// TGN forward v6: bf16 MFMA + unordered-CSR (atomic bump allocation).
//   k_hist   : degree histogram
//   k_alloc  : per-wave scan + one atomicAdd -> contiguous (unordered) regions
//   k_fill   : edge-list fill via cursor atomics (cursor = deg array)
//   k_cvt    : memory fp32 -> bf16 rows
//   k_pack   : pre-swizzle weights into MFMA B-fragment layout
//   k_edge_msg : edge message MLP (MFMA) -- v6: full A-preload (20 loads in
//                flight/wave), chunked 32x32 LDS transpose (9 KB total),
//                coalesced dwordx4 msg stores via LDS restage.
//   k_gather : LDS-free high-occupancy gather-mean (8 thr/node)
//   k_gru    : GRU MFMA only (reads means from global; no LDS)
//   k_embed  : embeddings + dot
// MFMA 16x16x32 bf16 layouts (HW-verified): A[m=l&15][k=(l>>4)*8+j],
// B[k=(l>>4)*8+j][n=l&15], D[m=(l>>4)*4+reg][n=l&15].
// ---------------------------------------------------------------------------

typedef __attribute__((ext_vector_type(8))) short bf16x8;
typedef __attribute__((ext_vector_type(4))) float f32x4;

static __device__ __forceinline__ unsigned short f2bf(float f) {
    unsigned int u = __float_as_uint(f);
    unsigned int r = (u + 0x7FFFu + ((u >> 16) & 1u)) >> 16;   // RNE
    return (unsigned short)r;
}
static __device__ __forceinline__ float bf2f(unsigned int v) {
    return __uint_as_float(v << 16);
}
static __device__ __forceinline__ bf16x8 as_bf(uint4 u) {
    union { uint4 u; bf16x8 v; } c; c.u = u; return c.v;
}
static __device__ __forceinline__ bf16x8 cvt8(float4 a, float4 b) {
    bf16x8 r;
    r[0]=(short)f2bf(a.x); r[1]=(short)f2bf(a.y); r[2]=(short)f2bf(a.z); r[3]=(short)f2bf(a.w);
    r[4]=(short)f2bf(b.x); r[5]=(short)f2bf(b.y); r[6]=(short)f2bf(b.z); r[7]=(short)f2bf(b.w);
    return r;
}
static __device__ __forceinline__ bf16x8 lds8(const unsigned short* p) {
    union { uint2 h[2]; bf16x8 v; } c;
    c.h[0] = *(const uint2*)p;
    c.h[1] = *(const uint2*)(p + 4);
    return c.v;
}
static __device__ __forceinline__ uint4 lds16(const unsigned short* p) {
    union { uint2 h[2]; uint4 v; } c;
    c.h[0] = *(const uint2*)p;
    c.h[1] = *(const uint2*)(p + 4);
    return c.v;
}
static __device__ __forceinline__ f32x4 mfma16(bf16x8 a, bf16x8 b, f32x4 c) {
    return __builtin_amdgcn_mfma_f32_16x16x32_bf16(a, b, c, 0, 0, 0);
}
static __device__ __forceinline__ f32x4 splat4(float v) {
    f32x4 c; c[0]=v; c[1]=v; c[2]=v; c[3]=v; return c;
}
static __device__ __forceinline__ float sigm(float x) {
    return 1.0f / (1.0f + expf(-x));
}
static __device__ __forceinline__ void acc8(float* a, uint4 u) {
    a[0] += bf2f(u.x & 0xffffu); a[1] += bf2f(u.x >> 16);
    a[2] += bf2f(u.y & 0xffffu); a[3] += bf2f(u.y >> 16);
    a[4] += bf2f(u.z & 0xffffu); a[5] += bf2f(u.z >> 16);
    a[6] += bf2f(u.w & 0xffffu); a[7] += bf2f(u.w >> 16);
}

// ------------------------- CSR build ---------------------------------------
__global__ __launch_bounds__(256) void k_hist(const int* __restrict__ src,
                                              const int* __restrict__ dst,
                                              int* __restrict__ deg, int E) {
    int e = blockIdx.x * 256 + threadIdx.x;
    if (e < E) {
        atomicAdd(&deg[src[e]], 1);
        atomicAdd(&deg[dst[e]], 1);
    }
}

// Unordered contiguous region allocation: wave-scan + 1 atomicAdd per wave.
// Writes offs[i] = region base; overwrites deg[i] with base (fill cursor).
__global__ __launch_bounds__(256) void k_alloc(int* __restrict__ deg,
                                               int* __restrict__ offs,
                                               int* __restrict__ counter, int N) {
    int i = blockIdx.x * 256 + threadIdx.x;
    int l = threadIdx.x & 63;
    int d = (i < N) ? deg[i] : 0;
    int s = d;                              // inclusive wave scan
    #pragma unroll
    for (int o = 1; o < 64; o <<= 1) {
        int u = __shfl_up(s, o, 64);
        if (l >= o) s += u;
    }
    int total = __shfl(s, 63, 64);
    int base = 0;
    if (l == 63) base = atomicAdd(counter, total);
    base = __shfl(base, 63, 64);
    int my = base + s - d;
    if (i < N) { offs[i] = my; deg[i] = my; }
}

__global__ __launch_bounds__(256) void k_fill(const int* __restrict__ src,
                                              const int* __restrict__ dst,
                                              int* __restrict__ cursor,
                                              int* __restrict__ elist, int E) {
    int e = blockIdx.x * 256 + threadIdx.x;
    if (e < E) {
        int p = atomicAdd(&cursor[src[e]], 1);
        elist[p] = e;
        int q = atomicAdd(&cursor[dst[e]], 1);
        elist[q] = e;
    }
}

// ------------------------- fp32 -> bf16 ------------------------------------
__global__ __launch_bounds__(256) void k_cvt(const float* __restrict__ x,
                                             unsigned short* __restrict__ y, int n) {
    int i = (blockIdx.x * 256 + threadIdx.x) * 8;
    if (i < n) {
        float4 a = *(const float4*)&x[i];
        float4 b = *(const float4*)&x[i + 4];
        *(bf16x8*)&y[i] = cvt8(a, b);
    }
}

// ------------------------- weight pre-swizzle ------------------------------
// frag f, lane l -> 8 bf16 of B[k=kstep*32+(l>>4)*8+j][n=ntile*16+(l&15)].
// ranges: w1p 0..79 | w2p 80..111 | wihp 112..207 | whhp 208..303 |
//         ew1p 304..327 | ew2p 328..335
__global__ __launch_bounds__(64) void k_pack(
    const float* __restrict__ w1, const float* __restrict__ w2,
    const float* __restrict__ wih, const float* __restrict__ whh,
    const float* __restrict__ ew1, const float* __restrict__ ew2,
    uint4* __restrict__ out)
{
    int f = blockIdx.x, l = threadIdx.x;
    const float* srcp; int NT, sk, sn, base;
    if (f < 80)       { srcp = w1;  NT = 8;  sk = 128; sn = 1;   base = 0;   }
    else if (f < 112) { srcp = w2;  NT = 8;  sk = 128; sn = 1;   base = 80;  }
    else if (f < 208) { srcp = wih; NT = 24; sk = 1;   sn = 128; base = 112; }
    else if (f < 304) { srcp = whh; NT = 24; sk = 1;   sn = 128; base = 208; }
    else if (f < 328) { srcp = ew1; NT = 4;  sk = 64;  sn = 1;   base = 304; }
    else              { srcp = ew2; NT = 4;  sk = 64;  sn = 1;   base = 328; }
    int fl = f - base;
    int kstep = fl / NT, ntile = fl - kstep * NT;
    int n  = ntile * 16 + (l & 15);
    int k0 = kstep * 32 + (l >> 4) * 8;
    unsigned short h[8];
    #pragma unroll
    for (int j = 0; j < 8; ++j)
        h[j] = f2bf(srcp[(size_t)(k0 + j) * sk + (size_t)n * sn]);
    uint4 p;
    p.x = h[0] | ((unsigned)h[1] << 16);
    p.y = h[2] | ((unsigned)h[3] << 16);
    p.z = h[4] | ((unsigned)h[5] << 16);
    p.w = h[6] | ((unsigned)h[7] << 16);
    out[(size_t)f * 64 + l] = p;
}

// ------------------------- Kernel A: edge messages -------------------------
// 256 threads = 4 waves; wave handles 32 edges (2 MFMA row-tiles).
// v6: all 20 A-loads issued up front (deep MLP per wave), 32x32 chunked LDS
// transpose (stride 36 ushorts: writes land q-groups on disjoint bank octets,
// 8B reads 2-way max), coalesced dwordx4 stores via LDS restage.
__global__ __launch_bounds__(256) void k_edge_msg(
    const int* __restrict__ src, const int* __restrict__ dst,
    const float* __restrict__ ef, const float* __restrict__ ts,
    const unsigned short* __restrict__ membf,
    const float* __restrict__ tw, const float* __restrict__ tb,
    const uint4* __restrict__ w1p, const float* __restrict__ b1,
    const uint4* __restrict__ w2p, const float* __restrict__ b2,
    unsigned short* __restrict__ msg, int E)
{
    __shared__ unsigned short h1s[4 * 32 * 36];   // 9216 B total, wave-private chunks
    const int tid = threadIdx.x;
    const int wv = tid >> 6, l = tid & 63;
    const int li = l & 15, q = l >> 4;
    const long long e0 = (long long)blockIdx.x * 128 + wv * 32;

    long long eA = e0 + li;       if (eA > E - 1) eA = E - 1;
    long long eB = e0 + 16 + li;  if (eB > E - 1) eB = E - 1;
    const int sA = src[eA], sB = src[eB], dA = dst[eA], dB = dst[eB];
    const float tsA = ts[eA], tsB = ts[eB];

    // ---- preload ALL A fragments: 16 random membf gathers + ef + te ----
    bf16x8 a0f[10], a1f[10];
    #pragma unroll
    for (int ks = 0; ks < 4; ++ks) {
        a0f[ks]     = *(const bf16x8*)(membf + (size_t)sA * 128 + ks * 32 + q * 8);
        a1f[ks]     = *(const bf16x8*)(membf + (size_t)sB * 128 + ks * 32 + q * 8);
        a0f[4 + ks] = *(const bf16x8*)(membf + (size_t)dA * 128 + ks * 32 + q * 8);
        a1f[4 + ks] = *(const bf16x8*)(membf + (size_t)dB * 128 + ks * 32 + q * 8);
    }
    {
        const float* pA = ef + (size_t)eA * 32 + q * 8;
        const float* pB = ef + (size_t)eB * 32 + q * 8;
        a0f[8] = cvt8(*(const float4*)pA, *(const float4*)(pA + 4));
        a1f[8] = cvt8(*(const float4*)pB, *(const float4*)(pB + 4));
    }
    {
        float4 twa = *(const float4*)&tw[q * 8];
        float4 twb = *(const float4*)&tw[q * 8 + 4];
        float4 tba = *(const float4*)&tb[q * 8];
        float4 tbb = *(const float4*)&tb[q * 8 + 4];
        float4 cA0, cA1, cB0, cB1;
        cA0.x = cosf(tsA*twa.x+tba.x); cA0.y = cosf(tsA*twa.y+tba.y);
        cA0.z = cosf(tsA*twa.z+tba.z); cA0.w = cosf(tsA*twa.w+tba.w);
        cA1.x = cosf(tsA*twb.x+tbb.x); cA1.y = cosf(tsA*twb.y+tbb.y);
        cA1.z = cosf(tsA*twb.z+tbb.z); cA1.w = cosf(tsA*twb.w+tbb.w);
        cB0.x = cosf(tsB*twa.x+tba.x); cB0.y = cosf(tsB*twa.y+tba.y);
        cB0.z = cosf(tsB*twa.z+tba.z); cB0.w = cosf(tsB*twa.w+tba.w);
        cB1.x = cosf(tsB*twb.x+tbb.x); cB1.y = cosf(tsB*twb.y+tbb.y);
        cB1.z = cosf(tsB*twb.z+tbb.z); cB1.w = cosf(tsB*twb.w+tbb.w);
        a0f[9] = cvt8(cA0, cA1);
        a1f[9] = cvt8(cB0, cB1);
    }
    __builtin_amdgcn_sched_barrier(0);   // keep the 20 loads issued before GEMM1

    // ---- GEMM1: h1 = relu(x @ w1 + b1), M=32, N=128, K=320 ----
    f32x4 acc[2][8];
    #pragma unroll
    for (int nt = 0; nt < 8; ++nt) {
        float bb = b1[nt * 16 + li];
        acc[0][nt] = splat4(bb);
        acc[1][nt] = splat4(bb);
    }
    #pragma unroll
    for (int ks = 0; ks < 10; ++ks) {
        #pragma unroll
        for (int nt = 0; nt < 8; ++nt) {
            bf16x8 b = as_bf(w1p[(size_t)(ks * 8 + nt) * 64 + l]);
            acc[0][nt] = mfma16(a0f[ks], b, acc[0][nt]);
            acc[1][nt] = mfma16(a1f[ks], b, acc[1][nt]);
        }
    }

    // ---- GEMM2: msg = relu(h1) @ w2 + b2, K=128, chunked 32x32 transpose ----
    unsigned short* hw = h1s + wv * 32 * 36;
    f32x4 acc2[2][8];
    #pragma unroll
    for (int nt = 0; nt < 8; ++nt) {
        float bb = b2[nt * 16 + li];
        acc2[0][nt] = splat4(bb);
        acc2[1][nt] = splat4(bb);
    }
    #pragma unroll
    for (int c = 0; c < 4; ++c) {
        // stage relu(h1) cols c*32..c*32+31 (wave-private, no barrier needed)
        #pragma unroll
        for (int rt = 0; rt < 2; ++rt)
            #pragma unroll
            for (int half = 0; half < 2; ++half) {
                int nt = c * 2 + half;
                #pragma unroll
                for (int r = 0; r < 4; ++r)
                    hw[(rt * 16 + q * 4 + r) * 36 + half * 16 + li] =
                        f2bf(fmaxf(acc[rt][nt][r], 0.0f));
            }
        bf16x8 a0 = lds8(hw + li * 36 + q * 8);
        bf16x8 a1 = lds8(hw + (16 + li) * 36 + q * 8);
        #pragma unroll
        for (int nt = 0; nt < 8; ++nt) {
            bf16x8 b = as_bf(w2p[(size_t)(c * 8 + nt) * 64 + l]);
            acc2[0][nt] = mfma16(a0, b, acc2[0][nt]);
            acc2[1][nt] = mfma16(a1, b, acc2[1][nt]);
        }
    }

    // ---- coalesced stores: restage acc2 via LDS chunks, dwordx4 out ----
    #pragma unroll
    for (int c = 0; c < 4; ++c) {
        #pragma unroll
        for (int rt = 0; rt < 2; ++rt)
            #pragma unroll
            for (int half = 0; half < 2; ++half) {
                int nt = c * 2 + half;
                #pragma unroll
                for (int r = 0; r < 4; ++r)
                    hw[(rt * 16 + q * 4 + r) * 36 + half * 16 + li] =
                        f2bf(acc2[rt][nt][r]);
            }
        #pragma unroll
        for (int t2 = 0; t2 < 2; ++t2) {
            int u = l + 64 * t2;            // 0..127
            int row = u >> 2;               // 0..31
            int seg = u & 3;                // 16B segment within 32-col chunk
            uint4 vv = lds16(hw + row * 36 + seg * 8);
            long long ge = e0 + row;
            if (ge < E)
                *(uint4*)(msg + (size_t)ge * 128 + c * 32 + seg * 8) = vv;
        }
    }
}

// ------------------------- Kernel B1: gather-mean --------------------------
// LDS-free, 8 threads/node: lane bits [part:2][dh:1] within each node-octet.
// Lanes 0-3 of an octet read parts 0-3 of the SAME msg row (coalesced 256B);
// dh=0/1 split the degree range interleaved (i = a+dh, i += 2).
// Double-buffered row prefetch hides the ~900cy HBM random-miss latency.
__global__ __launch_bounds__(256) void k_gather(
    const unsigned short* __restrict__ msg, const int* __restrict__ offs,
    const int* __restrict__ cur, const int* __restrict__ elist,
    unsigned short* __restrict__ means, int N)
{
    int t = blockIdx.x * 256 + threadIdx.x;
    int node = t >> 3;
    int part = t & 3;
    int dh = (t >> 2) & 1;
    if (node >= N) return;

    int a = offs[node], b = cur[node];
    float acc[32];
    #pragma unroll
    for (int c = 0; c < 32; ++c) acc[c] = 0.0f;

    int i = a + dh;
    uint4 m0, m1, m2, m3;
    m0 = m1 = m2 = m3 = uint4{0, 0, 0, 0};
    if (i < b) {
        const uint4* mr = (const uint4*)(msg + (size_t)elist[i] * 128 + part * 32);
        m0 = mr[0]; m1 = mr[1]; m2 = mr[2]; m3 = mr[3];
    }
    while (i < b) {
        int inext = i + 2;
        uint4 n0 = m0, n1 = m1, n2 = m2, n3 = m3;
        if (inext < b) {
            const uint4* nr = (const uint4*)(msg + (size_t)elist[inext] * 128 + part * 32);
            n0 = nr[0]; n1 = nr[1]; n2 = nr[2]; n3 = nr[3];
        }
        acc8(acc +  0, m0);
        acc8(acc +  8, m1);
        acc8(acc + 16, m2);
        acc8(acc + 24, m3);
        m0 = n0; m1 = n1; m2 = n2; m3 = n3;
        i = inext;
    }

    // combine the two degree slices (dh bit = lane bit 2)
    #pragma unroll
    for (int c = 0; c < 32; ++c) acc[c] += __shfl_xor(acc[c], 4, 64);

    if (dh == 0) {
        int d = b - a;
        float inv = (d > 0) ? 1.0f / (float)d : 0.0f;
        uint4 o[4];
        #pragma unroll
        for (int g = 0; g < 4; ++g) {
            o[g].x = f2bf(acc[g*8+0]*inv) | ((unsigned)f2bf(acc[g*8+1]*inv) << 16);
            o[g].y = f2bf(acc[g*8+2]*inv) | ((unsigned)f2bf(acc[g*8+3]*inv) << 16);
            o[g].z = f2bf(acc[g*8+4]*inv) | ((unsigned)f2bf(acc[g*8+5]*inv) << 16);
            o[g].w = f2bf(acc[g*8+6]*inv) | ((unsigned)f2bf(acc[g*8+7]*inv) << 16);
        }
        uint4* mp = (uint4*)(means + (size_t)node * 128 + part * 32);
        mp[0] = o[0]; mp[1] = o[1]; mp[2] = o[2]; mp[3] = o[3];
    }
}

// ------------------------- Kernel B2: GRU (MFMA only) ----------------------
// 256 threads = 4 waves; block = 128 nodes; wave = 32 nodes (2 row-tiles).
// Reads means (bf16) from global; no LDS.
__global__ __launch_bounds__(256) void k_gru(
    const unsigned short* __restrict__ means, const int* __restrict__ offs,
    const int* __restrict__ cur,
    const unsigned short* __restrict__ membf, const float* __restrict__ memf,
    const uint4* __restrict__ wihp, const uint4* __restrict__ whhp,
    const float* __restrict__ bih, const float* __restrict__ bhh,
    unsigned short* __restrict__ nmbf, int N)
{
    const int tid = threadIdx.x;
    const int n0 = blockIdx.x * 128;
    const int wv = tid >> 6, l = tid & 63;
    const int li = l & 15, q = l >> 4;
    const int nb = n0 + wv * 32;

    bf16x8 meanA[2][4], memA[2][4];
    #pragma unroll
    for (int rt = 0; rt < 2; ++rt) {
        int node = min(nb + rt * 16 + li, N - 1);
        #pragma unroll
        for (int ks = 0; ks < 4; ++ks) {
            meanA[rt][ks] = *(const bf16x8*)(means + (size_t)node * 128 + ks * 32 + q * 8);
            memA[rt][ks]  = *(const bf16x8*)(membf + (size_t)node * 128 + ks * 32 + q * 8);
        }
    }

    int degv[2][4];
    #pragma unroll
    for (int rt = 0; rt < 2; ++rt)
        #pragma unroll
        for (int r = 0; r < 4; ++r) {
            int node = min(nb + rt * 16 + q * 4 + r, N - 1);
            degv[rt][r] = cur[node] - offs[node];
        }

    #pragma unroll
    for (int t = 0; t < 8; ++t) {
        f32x4 ai[2][3], ah[2][3];
        #pragma unroll
        for (int g = 0; g < 3; ++g) {
            float bi = bih[g * 128 + t * 16 + li];
            float bh = bhh[g * 128 + t * 16 + li];
            ai[0][g] = splat4(bi); ai[1][g] = splat4(bi);
            ah[0][g] = splat4(bh); ah[1][g] = splat4(bh);
        }
        #pragma unroll
        for (int ks = 0; ks < 4; ++ks) {
            #pragma unroll
            for (int g = 0; g < 3; ++g) {
                bf16x8 bi = as_bf(wihp[(size_t)(ks * 24 + t + g * 8) * 64 + l]);
                bf16x8 bh = as_bf(whhp[(size_t)(ks * 24 + t + g * 8) * 64 + l]);
                ai[0][g] = mfma16(meanA[0][ks], bi, ai[0][g]);
                ai[1][g] = mfma16(meanA[1][ks], bi, ai[1][g]);
                ah[0][g] = mfma16(memA[0][ks], bh, ah[0][g]);
                ah[1][g] = mfma16(memA[1][ks], bh, ah[1][g]);
            }
        }
        #pragma unroll
        for (int rt = 0; rt < 2; ++rt)
            #pragma unroll
            for (int r = 0; r < 4; ++r) {
                int node = nb + rt * 16 + q * 4 + r;
                int nc = min(node, N - 1);
                float hp = memf[(size_t)nc * 128 + t * 16 + li];
                float rg = sigm(ai[rt][0][r] + ah[rt][0][r]);
                float zg = sigm(ai[rt][1][r] + ah[rt][1][r]);
                float ng = tanhf(ai[rt][2][r] + rg * ah[rt][2][r]);
                float hnew = (degv[rt][r] > 0) ? (1.0f - zg) * ng + zg * hp : hp;
                if (node < N)
                    nmbf[(size_t)node * 128 + t * 16 + li] = f2bf(hnew);
            }
    }
}

// ------------------------- Kernel C: embeddings + dot ----------------------
// 256 threads = 4 waves; block = 64 edges; waves 0,1 = src rows, 2,3 = dst.
__global__ __launch_bounds__(256) void k_embed(
    const int* __restrict__ src, const int* __restrict__ dst,
    const float* __restrict__ sf, const float* __restrict__ df,
    const unsigned short* __restrict__ nmbf,
    const uint4* __restrict__ ew1p, const float* __restrict__ b1,
    const uint4* __restrict__ ew2p, const float* __restrict__ b2,
    float* __restrict__ out, int E)
{
    __shared__ float embs[128 * 68];
    __shared__ unsigned short hs[4 * 32 * 68];
    const int tid = threadIdx.x;
    const int wv = tid >> 6, l = tid & 63;
    const int li = l & 15, q = l >> 4;
    const long long e0 = (long long)blockIdx.x * 64;

    const int side = wv >> 1;
    long long eA = e0 + (wv & 1) * 32 + li;      if (eA > E - 1) eA = E - 1;
    long long eB = e0 + (wv & 1) * 32 + 16 + li; if (eB > E - 1) eB = E - 1;
    const int idA = side ? dst[eA] : src[eA];
    const int idB = side ? dst[eB] : src[eB];
    const float* fp = side ? df : sf;

    // ---- GEMM1: h = relu(c @ ew1 + b1), M=32, N=64, K=192 ----
    f32x4 acc[2][4];
    #pragma unroll
    for (int nt = 0; nt < 4; ++nt) {
        float bb = b1[nt * 16 + li];
        acc[0][nt] = splat4(bb);
        acc[1][nt] = splat4(bb);
    }
    #pragma unroll
    for (int ks = 0; ks < 6; ++ks) {
        bf16x8 a0, a1;
        if (ks < 4) {
            a0 = *(const bf16x8*)(nmbf + (size_t)idA * 128 + ks * 32 + q * 8);
            a1 = *(const bf16x8*)(nmbf + (size_t)idB * 128 + ks * 32 + q * 8);
        } else {
            const float* pA = fp + (size_t)eA * 64 + (ks - 4) * 32 + q * 8;
            const float* pB = fp + (size_t)eB * 64 + (ks - 4) * 32 + q * 8;
            a0 = cvt8(*(const float4*)pA, *(const float4*)(pA + 4));
            a1 = cvt8(*(const float4*)pB, *(const float4*)(pB + 4));
        }
        #pragma unroll
        for (int nt = 0; nt < 4; ++nt) {
            bf16x8 b = as_bf(ew1p[(size_t)(ks * 4 + nt) * 64 + l]);
            acc[0][nt] = mfma16(a0, b, acc[0][nt]);
            acc[1][nt] = mfma16(a1, b, acc[1][nt]);
        }
    }

    unsigned short* hw = hs + wv * 32 * 68;
    #pragma unroll
    for (int rt = 0; rt < 2; ++rt)
        #pragma unroll
        for (int nt = 0; nt < 4; ++nt)
            #pragma unroll
            for (int r = 0; r < 4; ++r)
                hw[(rt * 16 + q * 4 + r) * 68 + nt * 16 + li] =
                    f2bf(fmaxf(acc[rt][nt][r], 0.0f));

    // ---- GEMM2: emb = h @ ew2 + b2, K=64 ----
    f32x4 acc2[2][4];
    #pragma unroll
    for (int nt = 0; nt < 4; ++nt) {
        float bb = b2[nt * 16 + li];
        acc2[0][nt] = splat4(bb);
        acc2[1][nt] = splat4(bb);
    }
    #pragma unroll
    for (int ks = 0; ks < 2; ++ks) {
        bf16x8 a0 = lds8(hw + (li) * 68 + ks * 32 + q * 8);
        bf16x8 a1 = lds8(hw + (16 + li) * 68 + ks * 32 + q * 8);
        #pragma unroll
        for (int nt = 0; nt < 4; ++nt) {
            bf16x8 b = as_bf(ew2p[(size_t)(ks * 4 + nt) * 64 + l]);
            acc2[0][nt] = mfma16(a0, b, acc2[0][nt]);
            acc2[1][nt] = mfma16(a1, b, acc2[1][nt]);
        }
    }

    // stage emb fp32 in LDS: rows 0..63 = src, 64..127 = dst
    #pragma unroll
    for (int rt = 0; rt < 2; ++rt)
        #pragma unroll
        for (int nt = 0; nt < 4; ++nt)
            #pragma unroll
            for (int r = 0; r < 4; ++r)
                embs[(wv * 32 + rt * 16 + q * 4 + r) * 68 + nt * 16 + li] =
                    acc2[rt][nt][r];
    __syncthreads();

    if (tid < 64) {
        long long ge = e0 + tid;
        const float* pa = embs + tid * 68;
        const float* pb = embs + (64 + tid) * 68;
        float s = 0.0f;
        #pragma unroll
        for (int c = 0; c < 64; c += 4) {
            float4 va = *(const float4*)(pa + c);
            float4 vb = *(const float4*)(pb + c);
            s += va.x * vb.x + va.y * vb.y + va.z * vb.z + va.w * vb.w;
        }
        if (ge < E) out[ge] = s;
    }
}

// ---------------------------------------------------------------------------
extern "C" void kernel_launch(void* const* d_in, const int* in_sizes, int n_in,
                              void* d_out, int out_size, void* d_ws, size_t ws_size,
                              hipStream_t stream)
{
    const int*   src = (const int*)d_in[0];
    const int*   dst = (const int*)d_in[1];
    const float* ef  = (const float*)d_in[2];
    const float* ts  = (const float*)d_in[3];
    const float* sf  = (const float*)d_in[4];
    const float* df  = (const float*)d_in[5];
    const float* mem = (const float*)d_in[6];
    const float* tw  = (const float*)d_in[7];
    const float* tb  = (const float*)d_in[8];
    const float* mw1 = (const float*)d_in[9];
    const float* mb1 = (const float*)d_in[10];
    const float* mw2 = (const float*)d_in[11];
    const float* mb2 = (const float*)d_in[12];
    const float* wih = (const float*)d_in[13];
    const float* whh = (const float*)d_in[14];
    const float* bih = (const float*)d_in[15];
    const float* bhh = (const float*)d_in[16];
    const float* ew1 = (const float*)d_in[17];
    const float* eb1 = (const float*)d_in[18];
    const float* ew2 = (const float*)d_in[19];
    const float* eb2 = (const float*)d_in[20];

    const int E = in_sizes[0];
    const int N = in_sizes[6] / 128;

    size_t off = 0;
    auto carve = [&](size_t bytes) {
        size_t cur = off;
        off = (off + bytes + 255) & ~(size_t)255;
        return cur;
    };
    char* w = (char*)d_ws;
    int*            deg    = (int*)(w + carve((size_t)N * 4));        // also cursor
    int*            offs   = (int*)(w + carve((size_t)N * 4));
    int*            counter= (int*)(w + carve(256));
    int*            elist  = (int*)(w + carve((size_t)2 * E * 4));
    unsigned short* membf  = (unsigned short*)(w + carve((size_t)N * 128 * 2));
    unsigned short* nmbf   = (unsigned short*)(w + carve((size_t)N * 128 * 2));
    unsigned short* means  = (unsigned short*)(w + carve((size_t)N * 128 * 2));
    unsigned short* msg    = (unsigned short*)(w + carve((size_t)E * 128 * 2));
    uint4*          packs  = (uint4*)(w + carve((size_t)336 * 64 * 16));

    const uint4* w1p  = packs;
    const uint4* w2p  = packs + (size_t)80 * 64;
    const uint4* wihp = packs + (size_t)112 * 64;
    const uint4* whhp = packs + (size_t)208 * 64;
    const uint4* ew1p = packs + (size_t)304 * 64;
    const uint4* ew2p = packs + (size_t)328 * 64;

    hipMemsetAsync(deg, 0, (size_t)N * 4, stream);
    hipMemsetAsync(counter, 0, 4, stream);

    k_hist<<<(E + 255) / 256, 256, 0, stream>>>(src, dst, deg, E);
    k_alloc<<<(N + 255) / 256, 256, 0, stream>>>(deg, offs, counter, N);
    k_fill<<<(E + 255) / 256, 256, 0, stream>>>(src, dst, deg, elist, E);
    k_cvt<<<(N * 128 / 8 + 255) / 256, 256, 0, stream>>>(mem, membf, N * 128);
    k_pack<<<336, 64, 0, stream>>>(mw1, mw2, wih, whh, ew1, ew2, packs);

    k_edge_msg<<<(E + 127) / 128, 256, 0, stream>>>(src, dst, ef, ts, membf, tw, tb,
                                                    w1p, mb1, w2p, mb2, msg, E);
    k_gather<<<((size_t)N * 8 + 255) / 256, 256, 0, stream>>>(msg, offs, deg, elist,
                                                              means, N);
    k_gru<<<(N + 127) / 128, 256, 0, stream>>>(means, offs, deg, membf, mem,
                                               wihp, whhp, bih, bhh, nmbf, N);
    k_embed<<<(E + 63) / 64, 256, 0, stream>>>(src, dst, sf, df, nmbf,
                                               ew1p, eb1, ew2p, eb2, (float*)d_out, E);
}

// Round 3
// 865.643 us; speedup vs baseline: 1.2319x; 1.2319x over previous
//
#include <hip/hip_runtime.h>
#include <math.h>

// ---------------------------------------------------------------------------
// TGN forward v7: bf16 MFMA + unordered-CSR (atomic bump allocation).
//   k_hist   : degree histogram
//   k_alloc  : per-wave scan + one atomicAdd -> contiguous (unordered) regions
//   k_fill   : edge-list fill via cursor atomics (cursor = deg array)
//   k_cvt    : memory fp32 -> bf16 rows
//   k_pack   : pre-swizzle weights into MFMA B-fragment layout
//   k_edge_msg : edge message MLP (MFMA). v7: v5 structure (JIT A-loads,
//                stride-132 LDS, scalar stores) + N-SPLIT across wave pairs:
//                each wave = 32 edges x 64 cols -> acc 32+32 AGPR (sequential),
//                ~2x occupancy vs v5. v6's full-preload/chunked-LDS reverted
//                (regs 276/wave -> 1 wave/SIMD, 1M bank conflicts).
//   k_gather : LDS-free high-occupancy gather-mean (8 thr/node)
//   k_gru    : GRU MFMA only (reads means from global; no LDS)
//   k_embed  : embeddings + dot
// MFMA 16x16x32 bf16 layouts (HW-verified): A[m=l&15][k=(l>>4)*8+j],
// B[k=(l>>4)*8+j][n=l&15], D[m=(l>>4)*4+reg][n=l&15].
// ---------------------------------------------------------------------------

typedef __attribute__((ext_vector_type(8))) short bf16x8;
typedef __attribute__((ext_vector_type(4))) float f32x4;

static __device__ __forceinline__ unsigned short f2bf(float f) {
    unsigned int u = __float_as_uint(f);
    unsigned int r = (u + 0x7FFFu + ((u >> 16) & 1u)) >> 16;   // RNE
    return (unsigned short)r;
}
static __device__ __forceinline__ float bf2f(unsigned int v) {
    return __uint_as_float(v << 16);
}
static __device__ __forceinline__ bf16x8 as_bf(uint4 u) {
    union { uint4 u; bf16x8 v; } c; c.u = u; return c.v;
}
static __device__ __forceinline__ bf16x8 cvt8(float4 a, float4 b) {
    bf16x8 r;
    r[0]=(short)f2bf(a.x); r[1]=(short)f2bf(a.y); r[2]=(short)f2bf(a.z); r[3]=(short)f2bf(a.w);
    r[4]=(short)f2bf(b.x); r[5]=(short)f2bf(b.y); r[6]=(short)f2bf(b.z); r[7]=(short)f2bf(b.w);
    return r;
}
static __device__ __forceinline__ bf16x8 lds8(const unsigned short* p) {
    union { uint2 h[2]; bf16x8 v; } c;
    c.h[0] = *(const uint2*)p;
    c.h[1] = *(const uint2*)(p + 4);
    return c.v;
}
static __device__ __forceinline__ f32x4 mfma16(bf16x8 a, bf16x8 b, f32x4 c) {
    return __builtin_amdgcn_mfma_f32_16x16x32_bf16(a, b, c, 0, 0, 0);
}
static __device__ __forceinline__ f32x4 splat4(float v) {
    f32x4 c; c[0]=v; c[1]=v; c[2]=v; c[3]=v; return c;
}
static __device__ __forceinline__ float sigm(float x) {
    return 1.0f / (1.0f + expf(-x));
}
static __device__ __forceinline__ void acc8(float* a, uint4 u) {
    a[0] += bf2f(u.x & 0xffffu); a[1] += bf2f(u.x >> 16);
    a[2] += bf2f(u.y & 0xffffu); a[3] += bf2f(u.y >> 16);
    a[4] += bf2f(u.z & 0xffffu); a[5] += bf2f(u.z >> 16);
    a[6] += bf2f(u.w & 0xffffu); a[7] += bf2f(u.w >> 16);
}

// ------------------------- CSR build ---------------------------------------
__global__ __launch_bounds__(256) void k_hist(const int* __restrict__ src,
                                              const int* __restrict__ dst,
                                              int* __restrict__ deg, int E) {
    int e = blockIdx.x * 256 + threadIdx.x;
    if (e < E) {
        atomicAdd(&deg[src[e]], 1);
        atomicAdd(&deg[dst[e]], 1);
    }
}

// Unordered contiguous region allocation: wave-scan + 1 atomicAdd per wave.
// Writes offs[i] = region base; overwrites deg[i] with base (fill cursor).
__global__ __launch_bounds__(256) void k_alloc(int* __restrict__ deg,
                                               int* __restrict__ offs,
                                               int* __restrict__ counter, int N) {
    int i = blockIdx.x * 256 + threadIdx.x;
    int l = threadIdx.x & 63;
    int d = (i < N) ? deg[i] : 0;
    int s = d;                              // inclusive wave scan
    #pragma unroll
    for (int o = 1; o < 64; o <<= 1) {
        int u = __shfl_up(s, o, 64);
        if (l >= o) s += u;
    }
    int total = __shfl(s, 63, 64);
    int base = 0;
    if (l == 63) base = atomicAdd(counter, total);
    base = __shfl(base, 63, 64);
    int my = base + s - d;
    if (i < N) { offs[i] = my; deg[i] = my; }
}

__global__ __launch_bounds__(256) void k_fill(const int* __restrict__ src,
                                              const int* __restrict__ dst,
                                              int* __restrict__ cursor,
                                              int* __restrict__ elist, int E) {
    int e = blockIdx.x * 256 + threadIdx.x;
    if (e < E) {
        int p = atomicAdd(&cursor[src[e]], 1);
        elist[p] = e;
        int q = atomicAdd(&cursor[dst[e]], 1);
        elist[q] = e;
    }
}

// ------------------------- fp32 -> bf16 ------------------------------------
__global__ __launch_bounds__(256) void k_cvt(const float* __restrict__ x,
                                             unsigned short* __restrict__ y, int n) {
    int i = (blockIdx.x * 256 + threadIdx.x) * 8;
    if (i < n) {
        float4 a = *(const float4*)&x[i];
        float4 b = *(const float4*)&x[i + 4];
        *(bf16x8*)&y[i] = cvt8(a, b);
    }
}

// ------------------------- weight pre-swizzle ------------------------------
// frag f, lane l -> 8 bf16 of B[k=kstep*32+(l>>4)*8+j][n=ntile*16+(l&15)].
// ranges: w1p 0..79 | w2p 80..111 | wihp 112..207 | whhp 208..303 |
//         ew1p 304..327 | ew2p 328..335
__global__ __launch_bounds__(64) void k_pack(
    const float* __restrict__ w1, const float* __restrict__ w2,
    const float* __restrict__ wih, const float* __restrict__ whh,
    const float* __restrict__ ew1, const float* __restrict__ ew2,
    uint4* __restrict__ out)
{
    int f = blockIdx.x, l = threadIdx.x;
    const float* srcp; int NT, sk, sn, base;
    if (f < 80)       { srcp = w1;  NT = 8;  sk = 128; sn = 1;   base = 0;   }
    else if (f < 112) { srcp = w2;  NT = 8;  sk = 128; sn = 1;   base = 80;  }
    else if (f < 208) { srcp = wih; NT = 24; sk = 1;   sn = 128; base = 112; }
    else if (f < 304) { srcp = whh; NT = 24; sk = 1;   sn = 128; base = 208; }
    else if (f < 328) { srcp = ew1; NT = 4;  sk = 64;  sn = 1;   base = 304; }
    else              { srcp = ew2; NT = 4;  sk = 64;  sn = 1;   base = 328; }
    int fl = f - base;
    int kstep = fl / NT, ntile = fl - kstep * NT;
    int n  = ntile * 16 + (l & 15);
    int k0 = kstep * 32 + (l >> 4) * 8;
    unsigned short h[8];
    #pragma unroll
    for (int j = 0; j < 8; ++j)
        h[j] = f2bf(srcp[(size_t)(k0 + j) * sk + (size_t)n * sn]);
    uint4 p;
    p.x = h[0] | ((unsigned)h[1] << 16);
    p.y = h[2] | ((unsigned)h[3] << 16);
    p.z = h[4] | ((unsigned)h[5] << 16);
    p.w = h[6] | ((unsigned)h[7] << 16);
    out[(size_t)f * 64 + l] = p;
}

// ------------------------- Kernel A: edge messages -------------------------
// 256 threads = 4 waves; block = 64 edges.
// Wave (eh,ch): eh = edge-half (32 edges), ch = col-half (64 msg cols).
// acc shrinks to 32 AGPR per generation (sequential) -> ~2x occupancy vs v5.
// h1 is staged in shared LDS (stride 132, conflict-free) and consumed by the
// wave pair after __syncthreads.
__global__ __launch_bounds__(256) void k_edge_msg(
    const int* __restrict__ src, const int* __restrict__ dst,
    const float* __restrict__ ef, const float* __restrict__ ts,
    const unsigned short* __restrict__ membf,
    const float* __restrict__ tw, const float* __restrict__ tb,
    const uint4* __restrict__ w1p, const float* __restrict__ b1,
    const uint4* __restrict__ w2p, const float* __restrict__ b2,
    unsigned short* __restrict__ msg, int E)
{
    __shared__ unsigned short h1s[64 * 132];   // 16896 B
    const int tid = threadIdx.x;
    const int wv = tid >> 6, l = tid & 63;
    const int li = l & 15, q = l >> 4;
    const int eh = wv >> 1;          // edge-half: 0 -> edges 0..31, 1 -> 32..63
    const int ch = wv & 1;           // col-half:  0 -> cols 0..63, 1 -> 64..127
    const long long e0 = (long long)blockIdx.x * 64 + eh * 32;

    long long eA = e0 + li;       if (eA > E - 1) eA = E - 1;
    long long eB = e0 + 16 + li;  if (eB > E - 1) eB = E - 1;
    const int sA = src[eA], sB = src[eB], dA = dst[eA], dB = dst[eB];
    const float tsA = ts[eA], tsB = ts[eB];

    // ---- GEMM1: h1 = relu(x @ w1 + b1), 32 edges x 64 cols, K=320 ----
    f32x4 acc[2][4];
    #pragma unroll
    for (int nt = 0; nt < 4; ++nt) {
        float bb = b1[(ch * 4 + nt) * 16 + li];
        acc[0][nt] = splat4(bb);
        acc[1][nt] = splat4(bb);
    }
    #pragma unroll
    for (int ks = 0; ks < 10; ++ks) {
        bf16x8 a0, a1;
        if (ks < 4) {
            a0 = *(const bf16x8*)(membf + (size_t)sA * 128 + ks * 32 + q * 8);
            a1 = *(const bf16x8*)(membf + (size_t)sB * 128 + ks * 32 + q * 8);
        } else if (ks < 8) {
            a0 = *(const bf16x8*)(membf + (size_t)dA * 128 + (ks - 4) * 32 + q * 8);
            a1 = *(const bf16x8*)(membf + (size_t)dB * 128 + (ks - 4) * 32 + q * 8);
        } else if (ks == 8) {
            const float* pA = ef + (size_t)eA * 32 + q * 8;
            const float* pB = ef + (size_t)eB * 32 + q * 8;
            a0 = cvt8(*(const float4*)pA, *(const float4*)(pA + 4));
            a1 = cvt8(*(const float4*)pB, *(const float4*)(pB + 4));
        } else {
            float4 twa = *(const float4*)&tw[q * 8];
            float4 twb = *(const float4*)&tw[q * 8 + 4];
            float4 tba = *(const float4*)&tb[q * 8];
            float4 tbb = *(const float4*)&tb[q * 8 + 4];
            float4 cA0, cA1, cB0, cB1;
            cA0.x = cosf(tsA*twa.x+tba.x); cA0.y = cosf(tsA*twa.y+tba.y);
            cA0.z = cosf(tsA*twa.z+tba.z); cA0.w = cosf(tsA*twa.w+tba.w);
            cA1.x = cosf(tsA*twb.x+tbb.x); cA1.y = cosf(tsA*twb.y+tbb.y);
            cA1.z = cosf(tsA*twb.z+tbb.z); cA1.w = cosf(tsA*twb.w+tbb.w);
            cB0.x = cosf(tsB*twa.x+tba.x); cB0.y = cosf(tsB*twa.y+tba.y);
            cB0.z = cosf(tsB*twa.z+tba.z); cB0.w = cosf(tsB*twa.w+tba.w);
            cB1.x = cosf(tsB*twb.x+tbb.x); cB1.y = cosf(tsB*twb.y+tbb.y);
            cB1.z = cosf(tsB*twb.z+tbb.z); cB1.w = cosf(tsB*twb.w+tbb.w);
            a0 = cvt8(cA0, cA1);
            a1 = cvt8(cB0, cB1);
        }
        #pragma unroll
        for (int nt = 0; nt < 4; ++nt) {
            bf16x8 b = as_bf(w1p[(size_t)(ks * 8 + ch * 4 + nt) * 64 + l]);
            acc[0][nt] = mfma16(a0, b, acc[0][nt]);
            acc[1][nt] = mfma16(a1, b, acc[1][nt]);
        }
    }

    // relu -> shared LDS (C layout -> row-major [64][132]); acc dies here.
    #pragma unroll
    for (int rt = 0; rt < 2; ++rt)
        #pragma unroll
        for (int nt = 0; nt < 4; ++nt)
            #pragma unroll
            for (int r = 0; r < 4; ++r)
                h1s[(eh * 32 + rt * 16 + q * 4 + r) * 132 + ch * 64 + nt * 16 + li] =
                    f2bf(fmaxf(acc[rt][nt][r], 0.0f));
    __syncthreads();

    // ---- GEMM2: msg = h1 @ w2 + b2, 32 edges x 64 cols, K=128 ----
    f32x4 acc2[2][4];
    #pragma unroll
    for (int nt = 0; nt < 4; ++nt) {
        float bb = b2[(ch * 4 + nt) * 16 + li];
        acc2[0][nt] = splat4(bb);
        acc2[1][nt] = splat4(bb);
    }
    #pragma unroll
    for (int ks = 0; ks < 4; ++ks) {
        bf16x8 a0 = lds8(h1s + (eh * 32 + li) * 132 + ks * 32 + q * 8);
        bf16x8 a1 = lds8(h1s + (eh * 32 + 16 + li) * 132 + ks * 32 + q * 8);
        #pragma unroll
        for (int nt = 0; nt < 4; ++nt) {
            bf16x8 b = as_bf(w2p[(size_t)(ks * 8 + ch * 4 + nt) * 64 + l]);
            acc2[0][nt] = mfma16(a0, b, acc2[0][nt]);
            acc2[1][nt] = mfma16(a1, b, acc2[1][nt]);
        }
    }

    // store bf16 msg rows (this wave's 64-col half)
    #pragma unroll
    for (int rt = 0; rt < 2; ++rt)
        #pragma unroll
        for (int r = 0; r < 4; ++r) {
            long long ge = e0 + rt * 16 + q * 4 + r;
            if (ge < E) {
                #pragma unroll
                for (int nt = 0; nt < 4; ++nt)
                    msg[(size_t)ge * 128 + ch * 64 + nt * 16 + li] =
                        f2bf(acc2[rt][nt][r]);
            }
        }
}

// ------------------------- Kernel B1: gather-mean --------------------------
// LDS-free, 8 threads/node: lane bits [part:2][dh:1] within each node-octet.
// Lanes 0-3 of an octet read parts 0-3 of the SAME msg row (coalesced 256B);
// dh=0/1 split the degree range interleaved (i = a+dh, i += 2).
// Double-buffered row prefetch hides the ~900cy HBM random-miss latency.
__global__ __launch_bounds__(256) void k_gather(
    const unsigned short* __restrict__ msg, const int* __restrict__ offs,
    const int* __restrict__ cur, const int* __restrict__ elist,
    unsigned short* __restrict__ means, int N)
{
    int t = blockIdx.x * 256 + threadIdx.x;
    int node = t >> 3;
    int part = t & 3;
    int dh = (t >> 2) & 1;
    if (node >= N) return;

    int a = offs[node], b = cur[node];
    float acc[32];
    #pragma unroll
    for (int c = 0; c < 32; ++c) acc[c] = 0.0f;

    int i = a + dh;
    uint4 m0, m1, m2, m3;
    m0 = m1 = m2 = m3 = uint4{0, 0, 0, 0};
    if (i < b) {
        const uint4* mr = (const uint4*)(msg + (size_t)elist[i] * 128 + part * 32);
        m0 = mr[0]; m1 = mr[1]; m2 = mr[2]; m3 = mr[3];
    }
    while (i < b) {
        int inext = i + 2;
        uint4 n0 = m0, n1 = m1, n2 = m2, n3 = m3;
        if (inext < b) {
            const uint4* nr = (const uint4*)(msg + (size_t)elist[inext] * 128 + part * 32);
            n0 = nr[0]; n1 = nr[1]; n2 = nr[2]; n3 = nr[3];
        }
        acc8(acc +  0, m0);
        acc8(acc +  8, m1);
        acc8(acc + 16, m2);
        acc8(acc + 24, m3);
        m0 = n0; m1 = n1; m2 = n2; m3 = n3;
        i = inext;
    }

    // combine the two degree slices (dh bit = lane bit 2)
    #pragma unroll
    for (int c = 0; c < 32; ++c) acc[c] += __shfl_xor(acc[c], 4, 64);

    if (dh == 0) {
        int d = b - a;
        float inv = (d > 0) ? 1.0f / (float)d : 0.0f;
        uint4 o[4];
        #pragma unroll
        for (int g = 0; g < 4; ++g) {
            o[g].x = f2bf(acc[g*8+0]*inv) | ((unsigned)f2bf(acc[g*8+1]*inv) << 16);
            o[g].y = f2bf(acc[g*8+2]*inv) | ((unsigned)f2bf(acc[g*8+3]*inv) << 16);
            o[g].z = f2bf(acc[g*8+4]*inv) | ((unsigned)f2bf(acc[g*8+5]*inv) << 16);
            o[g].w = f2bf(acc[g*8+6]*inv) | ((unsigned)f2bf(acc[g*8+7]*inv) << 16);
        }
        uint4* mp = (uint4*)(means + (size_t)node * 128 + part * 32);
        mp[0] = o[0]; mp[1] = o[1]; mp[2] = o[2]; mp[3] = o[3];
    }
}

// ------------------------- Kernel B2: GRU (MFMA only) ----------------------
// 256 threads = 4 waves; block = 128 nodes; wave = 32 nodes (2 row-tiles).
// Reads means (bf16) from global; no LDS.
__global__ __launch_bounds__(256) void k_gru(
    const unsigned short* __restrict__ means, const int* __restrict__ offs,
    const int* __restrict__ cur,
    const unsigned short* __restrict__ membf, const float* __restrict__ memf,
    const uint4* __restrict__ wihp, const uint4* __restrict__ whhp,
    const float* __restrict__ bih, const float* __restrict__ bhh,
    unsigned short* __restrict__ nmbf, int N)
{
    const int tid = threadIdx.x;
    const int n0 = blockIdx.x * 128;
    const int wv = tid >> 6, l = tid & 63;
    const int li = l & 15, q = l >> 4;
    const int nb = n0 + wv * 32;

    bf16x8 meanA[2][4], memA[2][4];
    #pragma unroll
    for (int rt = 0; rt < 2; ++rt) {
        int node = min(nb + rt * 16 + li, N - 1);
        #pragma unroll
        for (int ks = 0; ks < 4; ++ks) {
            meanA[rt][ks] = *(const bf16x8*)(means + (size_t)node * 128 + ks * 32 + q * 8);
            memA[rt][ks]  = *(const bf16x8*)(membf + (size_t)node * 128 + ks * 32 + q * 8);
        }
    }

    int degv[2][4];
    #pragma unroll
    for (int rt = 0; rt < 2; ++rt)
        #pragma unroll
        for (int r = 0; r < 4; ++r) {
            int node = min(nb + rt * 16 + q * 4 + r, N - 1);
            degv[rt][r] = cur[node] - offs[node];
        }

    #pragma unroll
    for (int t = 0; t < 8; ++t) {
        f32x4 ai[2][3], ah[2][3];
        #pragma unroll
        for (int g = 0; g < 3; ++g) {
            float bi = bih[g * 128 + t * 16 + li];
            float bh = bhh[g * 128 + t * 16 + li];
            ai[0][g] = splat4(bi); ai[1][g] = splat4(bi);
            ah[0][g] = splat4(bh); ah[1][g] = splat4(bh);
        }
        #pragma unroll
        for (int ks = 0; ks < 4; ++ks) {
            #pragma unroll
            for (int g = 0; g < 3; ++g) {
                bf16x8 bi = as_bf(wihp[(size_t)(ks * 24 + t + g * 8) * 64 + l]);
                bf16x8 bh = as_bf(whhp[(size_t)(ks * 24 + t + g * 8) * 64 + l]);
                ai[0][g] = mfma16(meanA[0][ks], bi, ai[0][g]);
                ai[1][g] = mfma16(meanA[1][ks], bi, ai[1][g]);
                ah[0][g] = mfma16(memA[0][ks], bh, ah[0][g]);
                ah[1][g] = mfma16(memA[1][ks], bh, ah[1][g]);
            }
        }
        #pragma unroll
        for (int rt = 0; rt < 2; ++rt)
            #pragma unroll
            for (int r = 0; r < 4; ++r) {
                int node = nb + rt * 16 + q * 4 + r;
                int nc = min(node, N - 1);
                float hp = memf[(size_t)nc * 128 + t * 16 + li];
                float rg = sigm(ai[rt][0][r] + ah[rt][0][r]);
                float zg = sigm(ai[rt][1][r] + ah[rt][1][r]);
                float ng = tanhf(ai[rt][2][r] + rg * ah[rt][2][r]);
                float hnew = (degv[rt][r] > 0) ? (1.0f - zg) * ng + zg * hp : hp;
                if (node < N)
                    nmbf[(size_t)node * 128 + t * 16 + li] = f2bf(hnew);
            }
    }
}

// ------------------------- Kernel C: embeddings + dot ----------------------
// 256 threads = 4 waves; block = 64 edges; waves 0,1 = src rows, 2,3 = dst.
__global__ __launch_bounds__(256) void k_embed(
    const int* __restrict__ src, const int* __restrict__ dst,
    const float* __restrict__ sf, const float* __restrict__ df,
    const unsigned short* __restrict__ nmbf,
    const uint4* __restrict__ ew1p, const float* __restrict__ b1,
    const uint4* __restrict__ ew2p, const float* __restrict__ b2,
    float* __restrict__ out, int E)
{
    __shared__ float embs[128 * 68];
    __shared__ unsigned short hs[4 * 32 * 68];
    const int tid = threadIdx.x;
    const int wv = tid >> 6, l = tid & 63;
    const int li = l & 15, q = l >> 4;
    const long long e0 = (long long)blockIdx.x * 64;

    const int side = wv >> 1;
    long long eA = e0 + (wv & 1) * 32 + li;      if (eA > E - 1) eA = E - 1;
    long long eB = e0 + (wv & 1) * 32 + 16 + li; if (eB > E - 1) eB = E - 1;
    const int idA = side ? dst[eA] : src[eA];
    const int idB = side ? dst[eB] : src[eB];
    const float* fp = side ? df : sf;

    // ---- GEMM1: h = relu(c @ ew1 + b1), M=32, N=64, K=192 ----
    f32x4 acc[2][4];
    #pragma unroll
    for (int nt = 0; nt < 4; ++nt) {
        float bb = b1[nt * 16 + li];
        acc[0][nt] = splat4(bb);
        acc[1][nt] = splat4(bb);
    }
    #pragma unroll
    for (int ks = 0; ks < 6; ++ks) {
        bf16x8 a0, a1;
        if (ks < 4) {
            a0 = *(const bf16x8*)(nmbf + (size_t)idA * 128 + ks * 32 + q * 8);
            a1 = *(const bf16x8*)(nmbf + (size_t)idB * 128 + ks * 32 + q * 8);
        } else {
            const float* pA = fp + (size_t)eA * 64 + (ks - 4) * 32 + q * 8;
            const float* pB = fp + (size_t)eB * 64 + (ks - 4) * 32 + q * 8;
            a0 = cvt8(*(const float4*)pA, *(const float4*)(pA + 4));
            a1 = cvt8(*(const float4*)pB, *(const float4*)(pB + 4));
        }
        #pragma unroll
        for (int nt = 0; nt < 4; ++nt) {
            bf16x8 b = as_bf(ew1p[(size_t)(ks * 4 + nt) * 64 + l]);
            acc[0][nt] = mfma16(a0, b, acc[0][nt]);
            acc[1][nt] = mfma16(a1, b, acc[1][nt]);
        }
    }

    unsigned short* hw = hs + wv * 32 * 68;
    #pragma unroll
    for (int rt = 0; rt < 2; ++rt)
        #pragma unroll
        for (int nt = 0; nt < 4; ++nt)
            #pragma unroll
            for (int r = 0; r < 4; ++r)
                hw[(rt * 16 + q * 4 + r) * 68 + nt * 16 + li] =
                    f2bf(fmaxf(acc[rt][nt][r], 0.0f));

    // ---- GEMM2: emb = h @ ew2 + b2, K=64 ----
    f32x4 acc2[2][4];
    #pragma unroll
    for (int nt = 0; nt < 4; ++nt) {
        float bb = b2[nt * 16 + li];
        acc2[0][nt] = splat4(bb);
        acc2[1][nt] = splat4(bb);
    }
    #pragma unroll
    for (int ks = 0; ks < 2; ++ks) {
        bf16x8 a0 = lds8(hw + (li) * 68 + ks * 32 + q * 8);
        bf16x8 a1 = lds8(hw + (16 + li) * 68 + ks * 32 + q * 8);
        #pragma unroll
        for (int nt = 0; nt < 4; ++nt) {
            bf16x8 b = as_bf(ew2p[(size_t)(ks * 4 + nt) * 64 + l]);
            acc2[0][nt] = mfma16(a0, b, acc2[0][nt]);
            acc2[1][nt] = mfma16(a1, b, acc2[1][nt]);
        }
    }

    // stage emb fp32 in LDS: rows 0..63 = src, 64..127 = dst
    #pragma unroll
    for (int rt = 0; rt < 2; ++rt)
        #pragma unroll
        for (int nt = 0; nt < 4; ++nt)
            #pragma unroll
            for (int r = 0; r < 4; ++r)
                embs[(wv * 32 + rt * 16 + q * 4 + r) * 68 + nt * 16 + li] =
                    acc2[rt][nt][r];
    __syncthreads();

    if (tid < 64) {
        long long ge = e0 + tid;
        const float* pa = embs + tid * 68;
        const float* pb = embs + (64 + tid) * 68;
        float s = 0.0f;
        #pragma unroll
        for (int c = 0; c < 64; c += 4) {
            float4 va = *(const float4*)(pa + c);
            float4 vb = *(const float4*)(pb + c);
            s += va.x * vb.x + va.y * vb.y + va.z * vb.z + va.w * vb.w;
        }
        if (ge < E) out[ge] = s;
    }
}

// ---------------------------------------------------------------------------
extern "C" void kernel_launch(void* const* d_in, const int* in_sizes, int n_in,
                              void* d_out, int out_size, void* d_ws, size_t ws_size,
                              hipStream_t stream)
{
    const int*   src = (const int*)d_in[0];
    const int*   dst = (const int*)d_in[1];
    const float* ef  = (const float*)d_in[2];
    const float* ts  = (const float*)d_in[3];
    const float* sf  = (const float*)d_in[4];
    const float* df  = (const float*)d_in[5];
    const float* mem = (const float*)d_in[6];
    const float* tw  = (const float*)d_in[7];
    const float* tb  = (const float*)d_in[8];
    const float* mw1 = (const float*)d_in[9];
    const float* mb1 = (const float*)d_in[10];
    const float* mw2 = (const float*)d_in[11];
    const float* mb2 = (const float*)d_in[12];
    const float* wih = (const float*)d_in[13];
    const float* whh = (const float*)d_in[14];
    const float* bih = (const float*)d_in[15];
    const float* bhh = (const float*)d_in[16];
    const float* ew1 = (const float*)d_in[17];
    const float* eb1 = (const float*)d_in[18];
    const float* ew2 = (const float*)d_in[19];
    const float* eb2 = (const float*)d_in[20];

    const int E = in_sizes[0];
    const int N = in_sizes[6] / 128;

    size_t off = 0;
    auto carve = [&](size_t bytes) {
        size_t cur = off;
        off = (off + bytes + 255) & ~(size_t)255;
        return cur;
    };
    char* w = (char*)d_ws;
    int*            deg    = (int*)(w + carve((size_t)N * 4));        // also cursor
    int*            offs   = (int*)(w + carve((size_t)N * 4));
    int*            counter= (int*)(w + carve(256));
    int*            elist  = (int*)(w + carve((size_t)2 * E * 4));
    unsigned short* membf  = (unsigned short*)(w + carve((size_t)N * 128 * 2));
    unsigned short* nmbf   = (unsigned short*)(w + carve((size_t)N * 128 * 2));
    unsigned short* means  = (unsigned short*)(w + carve((size_t)N * 128 * 2));
    unsigned short* msg    = (unsigned short*)(w + carve((size_t)E * 128 * 2));
    uint4*          packs  = (uint4*)(w + carve((size_t)336 * 64 * 16));

    const uint4* w1p  = packs;
    const uint4* w2p  = packs + (size_t)80 * 64;
    const uint4* wihp = packs + (size_t)112 * 64;
    const uint4* whhp = packs + (size_t)208 * 64;
    const uint4* ew1p = packs + (size_t)304 * 64;
    const uint4* ew2p = packs + (size_t)328 * 64;

    hipMemsetAsync(deg, 0, (size_t)N * 4, stream);
    hipMemsetAsync(counter, 0, 4, stream);

    k_hist<<<(E + 255) / 256, 256, 0, stream>>>(src, dst, deg, E);
    k_alloc<<<(N + 255) / 256, 256, 0, stream>>>(deg, offs, counter, N);
    k_fill<<<(E + 255) / 256, 256, 0, stream>>>(src, dst, deg, elist, E);
    k_cvt<<<(N * 128 / 8 + 255) / 256, 256, 0, stream>>>(mem, membf, N * 128);
    k_pack<<<336, 64, 0, stream>>>(mw1, mw2, wih, whh, ew1, ew2, packs);

    k_edge_msg<<<(E + 63) / 64, 256, 0, stream>>>(src, dst, ef, ts, membf, tw, tb,
                                                  w1p, mb1, w2p, mb2, msg, E);
    k_gather<<<((size_t)N * 8 + 255) / 256, 256, 0, stream>>>(msg, offs, deg, elist,
                                                              means, N);
    k_gru<<<(N + 127) / 128, 256, 0, stream>>>(means, offs, deg, membf, mem,
                                               wihp, whhp, bih, bhh, nmbf, N);
    k_embed<<<(E + 63) / 64, 256, 0, stream>>>(src, dst, sf, df, nmbf,
                                               ew1p, eb1, ew2p, eb2, (float*)d_out, E);
}